// Round 1
// baseline (46.575 us; speedup 1.0000x reference)
//
#include <hip/hip_runtime.h>
#include <math.h>

__device__ __forceinline__ float smooth_l1f(float x, float y) {
    float d = fabsf(x - y);
    return d < 1.0f ? 0.5f * d * d : d - 0.5f;
}

// row-major 3x3 -> quaternion, matching the reference's branch selection
// (tr>0 -> case 0, else 1+argmax(diag) with first-max tie-break)
__device__ void mat2quat_dev(const float* R, float* q) {
    float R00=R[0],R01=R[1],R02=R[2];
    float R10=R[3],R11=R[4],R12=R[5];
    float R20=R[6],R21=R[7],R22=R[8];
    float tr = R00 + R11 + R22;
    float t;
    if (tr > 0.0f) {
        t = 1.0f + tr;
        q[0]=t; q[1]=R21-R12; q[2]=R02-R20; q[3]=R10-R01;
    } else {
        int sel = 1; float best = R00;
        if (R11 > best) { sel = 2; best = R11; }
        if (R22 > best) { sel = 3; }
        if (sel == 1)      { t = 1.0f+R00-R11-R22; q[0]=R21-R12; q[1]=t; q[2]=R01+R10; q[3]=R02+R20; }
        else if (sel == 2) { t = 1.0f-R00+R11-R22; q[0]=R02-R20; q[1]=R01+R10; q[2]=t; q[3]=R12+R21; }
        else               { t = 1.0f-R00-R11+R22; q[0]=R10-R01; q[1]=R02+R20; q[2]=R12+R21; q[3]=t; }
    }
    float s = 0.5f / sqrtf(fmaxf(t, 1e-12f));
    q[0]*=s; q[1]*=s; q[2]*=s; q[3]*=s;
}

// One block of 64 threads; thread b < B handles batch b.
// Computes all the small matrix algebra + scalar loss terms, writes the
// fused per-batch transform (M = gR^T*pR - I, Tt = gR^T*(pt-gt)) for the
// point kernel, and zeroes the per-batch accumulators (fresh every call).
__global__ void prep_kernel(const float* __restrict__ pred_t,
                            const float* __restrict__ pred_q,
                            const float* __restrict__ gtT,
                            const float* __restrict__ initT,
                            double* errsum, double* masksum,
                            float* scalar_part, float* mt, int B)
{
    int b = threadIdx.x;
    float partial = 0.0f;
    if (b < B) {
        errsum[b] = 0.0; masksum[b] = 0.0;
        float tx=pred_t[b*3+0], ty=pred_t[b*3+1], tz=pred_t[b*3+2];
        float q0=pred_q[b*4+0], q1=pred_q[b*4+1], q2=pred_q[b*4+2], q3=pred_q[b*4+3];
        float nsq = q0*q0+q1*q1+q2*q2+q3*q3;
        float qn_term = (nsq-1.0f)*(nsq-1.0f);
        float inv = rsqrtf(nsq);
        float w=q0*inv, x=q1*inv, y=q2*inv, z=q3*inv;
        float R[9];
        R[0]=1.0f-2.0f*(y*y+z*z); R[1]=2.0f*(x*y-w*z);      R[2]=2.0f*(x*z+w*y);
        R[3]=2.0f*(x*y+w*z);      R[4]=1.0f-2.0f*(x*x+z*z); R[5]=2.0f*(y*z-w*x);
        R[6]=2.0f*(x*z-w*y);      R[7]=2.0f*(y*z+w*x);      R[8]=1.0f-2.0f*(x*x+y*y);

        float iR[9], it[3], gR[9], gt_[3];
        for (int i=0;i<3;i++){
            for (int j=0;j<3;j++){
                iR[i*3+j]=initT[b*16+i*4+j];
                gR[i*3+j]=gtT [b*16+i*4+j];
            }
            it[i]=initT[b*16+i*4+3];
            gt_[i]=gtT [b*16+i*4+3];
        }
        // inv(T_pred) @ init : pR = R^T iR, pt = R^T (it - t)
        float pR[9], pt[3];
        for (int i=0;i<3;i++){
            for (int j=0;j<3;j++){
                pR[i*3+j] = R[0+i]*iR[0+j] + R[3+i]*iR[3+j] + R[6+i]*iR[6+j];
            }
            pt[i] = R[0+i]*(it[0]-tx) + R[3+i]*(it[1]-ty) + R[6+i]*(it[2]-tz);
        }
        float t_term = smooth_l1f(pt[0],gt_[0]) + smooth_l1f(pt[1],gt_[1]) + smooth_l1f(pt[2],gt_[2]);

        // RT = inv(gt) @ [pR pt] : RT_R = gR^T pR, RT_t = gR^T (pt - gt)
        float M[9], Tt[3];
        for (int i=0;i<3;i++){
            for (int j=0;j<3;j++){
                M[i*3+j] = gR[0+i]*pR[0+j] + gR[3+i]*pR[3+j] + gR[6+i]*pR[6+j];
            }
            Tt[i] = gR[0+i]*(pt[0]-gt_[0]) + gR[3+i]*(pt[1]-gt_[1]) + gR[6+i]*(pt[2]-gt_[2]);
        }
        M[0]-=1.0f; M[4]-=1.0f; M[8]-=1.0f;   // pts - pcs = M*p + Tt
        #pragma unroll
        for (int k=0;k<9;k++) mt[b*12+k]=M[k];
        mt[b*12+9]=Tt[0]; mt[b*12+10]=Tt[1]; mt[b*12+11]=Tt[2];

        // r_loss term: quat_distance(mat2quat(pR), mat2quat(gR))
        float qp[4], qg[4];
        mat2quat_dev(pR,qp); mat2quat_dev(gR,qg);
        // d = qp * conj(qg)
        float dw = qp[0]*qg[0] + qp[1]*qg[1] + qp[2]*qg[2] + qp[3]*qg[3];
        float cx = qp[2]*qg[3]-qp[3]*qg[2];
        float cy = qp[3]*qg[1]-qp[1]*qg[3];
        float cz = qp[1]*qg[2]-qp[2]*qg[1];
        float dvx = -qp[0]*qg[1] + qg[0]*qp[1] - cx;
        float dvy = -qp[0]*qg[2] + qg[0]*qp[2] - cy;
        float dvz = -qp[0]*qg[3] + qg[0]*qp[3] - cz;
        float r_term = 2.0f*atan2f(sqrtf(dvx*dvx+dvy*dvy+dvz*dvz), fabsf(dw));

        partial = (1.0f*t_term + 0.5f*r_term + 0.5f*qn_term) / (float)B;
    }
    // one-wave reduce over 64 lanes (inactive lanes carry 0)
    for (int off=32; off>0; off>>=1) partial += __shfl_down(partial, off);
    if (threadIdx.x==0) *scalar_part = partial;
}

__global__ __launch_bounds__(256) void pc_kernel(const float* __restrict__ pcs,
                                                 const int* __restrict__ mask,
                                                 const float* __restrict__ mt,
                                                 double* errsum, double* masksum,
                                                 int N, int bpb)
{
    int b   = blockIdx.x / bpb;
    int blk = blockIdx.x - b*bpb;
    const float* wv = mt + b*12;
    float m00=wv[0], m01=wv[1], m02=wv[2];
    float m10=wv[3], m11=wv[4], m12=wv[5];
    float m20=wv[6], m21=wv[7], m22=wv[8];
    float t0 =wv[9], t1 =wv[10], t2 =wv[11];

    const float4* p4  = (const float4*)(pcs  + (size_t)b * N * 3);
    const int4*   mk4 = (const int4*)  (mask + (size_t)b * N);
    int ng = N >> 2;
    float esum = 0.0f, msum = 0.0f;

    for (int g = blk*256 + (int)threadIdx.x; g < ng; g += bpb*256) {
        float4 A = p4[(size_t)g*3+0];
        float4 C = p4[(size_t)g*3+1];
        float4 D = p4[(size_t)g*3+2];
        int4  mk = mk4[g];
        float px[4] = {A.x, A.w, C.z, D.y};
        float py[4] = {A.y, C.x, C.w, D.z};
        float pz[4] = {A.z, C.y, D.x, D.w};
        float mm[4] = {(float)mk.x, (float)mk.y, (float)mk.z, (float)mk.w};
        #pragma unroll
        for (int k=0;k<4;k++){
            float dx = m00*px[k] + m01*py[k] + m02*pz[k] + t0;
            float dy = m10*px[k] + m11*py[k] + m12*pz[k] + t1;
            float dz = m20*px[k] + m21*py[k] + m22*pz[k] + t2;
            esum += mm[k] * sqrtf(dx*dx + dy*dy + dz*dz);
            msum += mm[k];
        }
    }
    // tail (N % 4) handled by block 0
    int rem = N & 3;
    if (rem && blk == 0 && (int)threadIdx.x < rem) {
        int idx = ng*4 + (int)threadIdx.x;
        const float* p = pcs + ((size_t)b*N + idx)*3;
        float mm = (float)mask[(size_t)b*N + idx];
        float dx = m00*p[0]+m01*p[1]+m02*p[2]+t0;
        float dy = m10*p[0]+m11*p[1]+m12*p[2]+t1;
        float dz = m20*p[0]+m21*p[1]+m22*p[2]+t2;
        esum += mm*sqrtf(dx*dx+dy*dy+dz*dz);
        msum += mm;
    }

    for (int off=32; off>0; off>>=1){
        esum += __shfl_down(esum, off);
        msum += __shfl_down(msum, off);
    }
    __shared__ float sE[4], sM[4];
    int lane = threadIdx.x & 63, wid = threadIdx.x >> 6;
    if (lane==0){ sE[wid]=esum; sM[wid]=msum; }
    __syncthreads();
    if (threadIdx.x==0){
        atomicAdd(&errsum[b],  (double)(sE[0]+sE[1]+sE[2]+sE[3]));
        atomicAdd(&masksum[b], (double)(sM[0]+sM[1]+sM[2]+sM[3]));
    }
}

__global__ void finish_kernel(const double* __restrict__ errsum,
                              const double* __restrict__ masksum,
                              const float* __restrict__ scalar_part,
                              float* out, int B)
{
    if (threadIdx.x==0 && blockIdx.x==0){
        double pc = 0.0;
        for (int b=0;b<B;b++) pc += errsum[b] / masksum[b];
        out[0] = *scalar_part + 0.5f * (float)(pc / (double)B);
    }
}

extern "C" void kernel_launch(void* const* d_in, const int* in_sizes, int n_in,
                              void* d_out, int out_size, void* d_ws, size_t ws_size,
                              hipStream_t stream)
{
    const float* pred_t = (const float*)d_in[0];
    const float* pred_q = (const float*)d_in[1];
    const float* pcs    = (const float*)d_in[2];
    const float* gtT    = (const float*)d_in[3];
    const float* initT  = (const float*)d_in[4];
    const int*   mask   = (const int*)d_in[5];

    int B = in_sizes[0] / 3;
    int N = in_sizes[2] / (B * 3);

    double* errsum      = (double*)d_ws;           // [B]
    double* masksum     = errsum + B;              // [B]
    float*  scalar_part = (float*)(masksum + B);   // [1] (+pad)
    float*  mt          = scalar_part + 4;         // [B*12], 16B-aligned

    float* out = (float*)d_out;

    prep_kernel<<<1, 64, 0, stream>>>(pred_t, pred_q, gtT, initT,
                                      errsum, masksum, scalar_part, mt, B);
    int bpb = 256;  // blocks per batch -> 2048 total blocks
    pc_kernel<<<B*bpb, 256, 0, stream>>>(pcs, mask, mt, errsum, masksum, N, bpb);
    finish_kernel<<<1, 1, 0, stream>>>(errsum, masksum, scalar_part, out, B);
}

// Round 2
// 42.541 us; speedup vs baseline: 1.0948x; 1.0948x over previous
//
#include <hip/hip_runtime.h>
#include <math.h>

struct Pose {
    float M[9], Tt[3], pR[9], pt[3], gR[9], gt[3], qn;
};

__device__ __forceinline__ float smooth_l1f(float x, float y) {
    float d = fabsf(x - y);
    return d < 1.0f ? 0.5f * d * d : d - 0.5f;
}

// row-major 3x3 -> quaternion, matching the reference's branch selection
// (tr>0 -> case 0, else 1+argmax(diag) with first-max tie-break)
__device__ void mat2quat_dev(const float* R, float* q) {
    float R00=R[0],R01=R[1],R02=R[2];
    float R10=R[3],R11=R[4],R12=R[5];
    float R20=R[6],R21=R[7],R22=R[8];
    float tr = R00 + R11 + R22;
    float t;
    if (tr > 0.0f) {
        t = 1.0f + tr;
        q[0]=t; q[1]=R21-R12; q[2]=R02-R20; q[3]=R10-R01;
    } else {
        int sel = 1; float best = R00;
        if (R11 > best) { sel = 2; best = R11; }
        if (R22 > best) { sel = 3; }
        if (sel == 1)      { t = 1.0f+R00-R11-R22; q[0]=R21-R12; q[1]=t; q[2]=R01+R10; q[3]=R02+R20; }
        else if (sel == 2) { t = 1.0f-R00+R11-R22; q[0]=R02-R20; q[1]=R01+R10; q[2]=t; q[3]=R12+R21; }
        else               { t = 1.0f-R00-R11+R22; q[0]=R10-R01; q[1]=R02+R20; q[2]=R12+R21; q[3]=t; }
    }
    float s = 0.5f / sqrtf(fmaxf(t, 1e-12f));
    q[0]*=s; q[1]*=s; q[2]*=s; q[3]*=s;
}

// All the small per-batch matrix algebra: fused transform for the point loss
// (M = gR^T*pR - I, Tt = gR^T*(pt-gt)) plus intermediates for t/r/qn terms.
__device__ void compute_pose(int b,
                             const float* __restrict__ pred_t,
                             const float* __restrict__ pred_q,
                             const float* __restrict__ gtT,
                             const float* __restrict__ initT,
                             Pose& P)
{
    float tx=pred_t[b*3+0], ty=pred_t[b*3+1], tz=pred_t[b*3+2];
    float q0=pred_q[b*4+0], q1=pred_q[b*4+1], q2=pred_q[b*4+2], q3=pred_q[b*4+3];
    float nsq = q0*q0+q1*q1+q2*q2+q3*q3;
    P.qn = (nsq-1.0f)*(nsq-1.0f);
    float inv = rsqrtf(nsq);
    float w=q0*inv, x=q1*inv, y=q2*inv, z=q3*inv;
    float R[9];
    R[0]=1.0f-2.0f*(y*y+z*z); R[1]=2.0f*(x*y-w*z);      R[2]=2.0f*(x*z+w*y);
    R[3]=2.0f*(x*y+w*z);      R[4]=1.0f-2.0f*(x*x+z*z); R[5]=2.0f*(y*z-w*x);
    R[6]=2.0f*(x*z-w*y);      R[7]=2.0f*(y*z+w*x);      R[8]=1.0f-2.0f*(x*x+y*y);

    float iR[9], it[3];
    for (int i=0;i<3;i++){
        for (int j=0;j<3;j++){
            iR[i*3+j]=initT[b*16+i*4+j];
            P.gR[i*3+j]=gtT[b*16+i*4+j];
        }
        it[i]=initT[b*16+i*4+3];
        P.gt[i]=gtT[b*16+i*4+3];
    }
    // inv(T_pred) @ init : pR = R^T iR, pt = R^T (it - t)
    for (int i=0;i<3;i++){
        for (int j=0;j<3;j++)
            P.pR[i*3+j] = R[0+i]*iR[0+j] + R[3+i]*iR[3+j] + R[6+i]*iR[6+j];
        P.pt[i] = R[0+i]*(it[0]-tx) + R[3+i]*(it[1]-ty) + R[6+i]*(it[2]-tz);
    }
    // RT = inv(gt) @ [pR pt] : M = gR^T pR - I, Tt = gR^T (pt - gt)
    for (int i=0;i<3;i++){
        for (int j=0;j<3;j++)
            P.M[i*3+j] = P.gR[0+i]*P.pR[0+j] + P.gR[3+i]*P.pR[3+j] + P.gR[6+i]*P.pR[6+j];
        P.Tt[i] = P.gR[0+i]*(P.pt[0]-P.gt[0]) + P.gR[3+i]*(P.pt[1]-P.gt[1]) + P.gR[6+i]*(P.pt[2]-P.gt[2]);
    }
    P.M[0]-=1.0f; P.M[4]-=1.0f; P.M[8]-=1.0f;   // pts - pcs = M*p + Tt
}

// Fused main kernel: per-block pose computed in LDS (thread 0), grid-stride
// point loop, block reduce, write one float pair per block to unique slots
// (always written -> no zero-init, no atomics).
__global__ __launch_bounds__(256) void pc_fused(const float* __restrict__ pcs,
                                                const int* __restrict__ mask,
                                                const float* __restrict__ pred_t,
                                                const float* __restrict__ pred_q,
                                                const float* __restrict__ gtT,
                                                const float* __restrict__ initT,
                                                float* __restrict__ errS,
                                                float* __restrict__ maskS,
                                                int N, int bpb)
{
    int b   = blockIdx.x / bpb;
    int blk = blockIdx.x - b*bpb;

    __shared__ float sMT[12];
    if (threadIdx.x == 0) {
        Pose P;
        compute_pose(b, pred_t, pred_q, gtT, initT, P);
        #pragma unroll
        for (int k=0;k<9;k++) sMT[k]=P.M[k];
        sMT[9]=P.Tt[0]; sMT[10]=P.Tt[1]; sMT[11]=P.Tt[2];
    }
    __syncthreads();
    float m00=sMT[0], m01=sMT[1], m02=sMT[2];
    float m10=sMT[3], m11=sMT[4], m12=sMT[5];
    float m20=sMT[6], m21=sMT[7], m22=sMT[8];
    float t0 =sMT[9], t1 =sMT[10], t2 =sMT[11];

    const float4* p4  = (const float4*)(pcs  + (size_t)b * N * 3);
    const int4*   mk4 = (const int4*)  (mask + (size_t)b * N);
    int ng = N >> 2;
    float esum = 0.0f, msum = 0.0f;

    for (int g = blk*256 + (int)threadIdx.x; g < ng; g += bpb*256) {
        float4 A = p4[(size_t)g*3+0];
        float4 C = p4[(size_t)g*3+1];
        float4 D = p4[(size_t)g*3+2];
        int4  mk = mk4[g];
        float px[4] = {A.x, A.w, C.z, D.y};
        float py[4] = {A.y, C.x, C.w, D.z};
        float pz[4] = {A.z, C.y, D.x, D.w};
        float mm[4] = {(float)mk.x, (float)mk.y, (float)mk.z, (float)mk.w};
        #pragma unroll
        for (int k=0;k<4;k++){
            float dx = m00*px[k] + m01*py[k] + m02*pz[k] + t0;
            float dy = m10*px[k] + m11*py[k] + m12*pz[k] + t1;
            float dz = m20*px[k] + m21*py[k] + m22*pz[k] + t2;
            esum += mm[k] * sqrtf(dx*dx + dy*dy + dz*dz);
            msum += mm[k];
        }
    }
    // tail (N % 4) handled by block 0 of each batch
    int rem = N & 3;
    if (rem && blk == 0 && (int)threadIdx.x < rem) {
        int idx = ng*4 + (int)threadIdx.x;
        const float* p = pcs + ((size_t)b*N + idx)*3;
        float mm = (float)mask[(size_t)b*N + idx];
        float dx = m00*p[0]+m01*p[1]+m02*p[2]+t0;
        float dy = m10*p[0]+m11*p[1]+m12*p[2]+t1;
        float dz = m20*p[0]+m21*p[1]+m22*p[2]+t2;
        esum += mm*sqrtf(dx*dx+dy*dy+dz*dz);
        msum += mm;
    }

    for (int off=32; off>0; off>>=1){
        esum += __shfl_down(esum, off);
        msum += __shfl_down(msum, off);
    }
    __shared__ float sE[4], sM[4];
    int lane = threadIdx.x & 63, wid = threadIdx.x >> 6;
    if (lane==0){ sE[wid]=esum; sM[wid]=msum; }
    __syncthreads();
    if (threadIdx.x==0){
        errS [blockIdx.x] = sE[0]+sE[1]+sE[2]+sE[3];
        maskS[blockIdx.x] = sM[0]+sM[1]+sM[2]+sM[3];
    }
}

// One wave: reduce the per-block slots per batch, add the scalar loss terms.
__global__ void finish_kernel(const float* __restrict__ errS,
                              const float* __restrict__ maskS,
                              const float* __restrict__ pred_t,
                              const float* __restrict__ pred_q,
                              const float* __restrict__ gtT,
                              const float* __restrict__ initT,
                              float* __restrict__ out, int B, int bpb)
{
    int t = threadIdx.x;   // 64 threads
    // --- point-cloud part ---
    double pcAcc = 0.0;    // meaningful on lane 0 only
    for (int b=0;b<B;b++){
        float e=0.0f, m=0.0f;
        for (int k=t; k<bpb; k+=64){ e += errS[b*bpb+k]; m += maskS[b*bpb+k]; }
        for (int off=32; off>0; off>>=1){
            e += __shfl_down(e, off);
            m += __shfl_down(m, off);
        }
        if (t==0) pcAcc += (double)e / (double)m;
    }
    // --- scalar part (t/r/qn), lane b handles batch b ---
    float partial = 0.0f;
    if (t < B) {
        Pose P;
        compute_pose(t, pred_t, pred_q, gtT, initT, P);
        float t_term = smooth_l1f(P.pt[0],P.gt[0]) + smooth_l1f(P.pt[1],P.gt[1])
                     + smooth_l1f(P.pt[2],P.gt[2]);
        float qp[4], qg[4];
        mat2quat_dev(P.pR,qp); mat2quat_dev(P.gR,qg);
        // d = qp * conj(qg)
        float dw  = qp[0]*qg[0] + qp[1]*qg[1] + qp[2]*qg[2] + qp[3]*qg[3];
        float cx  = qp[2]*qg[3]-qp[3]*qg[2];
        float cy  = qp[3]*qg[1]-qp[1]*qg[3];
        float cz  = qp[1]*qg[2]-qp[2]*qg[1];
        float dvx = -qp[0]*qg[1] + qg[0]*qp[1] - cx;
        float dvy = -qp[0]*qg[2] + qg[0]*qp[2] - cy;
        float dvz = -qp[0]*qg[3] + qg[0]*qp[3] - cz;
        float r_term = 2.0f*atan2f(sqrtf(dvx*dvx+dvy*dvy+dvz*dvz), fabsf(dw));
        partial = (1.0f*t_term + 0.5f*r_term + 0.5f*P.qn) / (float)B;
    }
    for (int off=32; off>0; off>>=1) partial += __shfl_down(partial, off);
    if (t==0) out[0] = partial + 0.5f * (float)(pcAcc / (double)B);
}

extern "C" void kernel_launch(void* const* d_in, const int* in_sizes, int n_in,
                              void* d_out, int out_size, void* d_ws, size_t ws_size,
                              hipStream_t stream)
{
    const float* pred_t = (const float*)d_in[0];
    const float* pred_q = (const float*)d_in[1];
    const float* pcs    = (const float*)d_in[2];
    const float* gtT    = (const float*)d_in[3];
    const float* initT  = (const float*)d_in[4];
    const int*   mask   = (const int*)d_in[5];

    int B = in_sizes[0] / 3;
    int N = in_sizes[2] / (B * 3);

    int bpb = 256;  // blocks per batch -> B*bpb total blocks
    float* errS  = (float*)d_ws;       // [B*bpb] always fully written
    float* maskS = errS + B*bpb;       // [B*bpb]
    float* out   = (float*)d_out;

    pc_fused<<<B*bpb, 256, 0, stream>>>(pcs, mask, pred_t, pred_q, gtT, initT,
                                        errS, maskS, N, bpb);
    finish_kernel<<<1, 64, 0, stream>>>(errS, maskS, pred_t, pred_q, gtT, initT,
                                        out, B, bpb);
}

// Round 3
// 32.391 us; speedup vs baseline: 1.4379x; 1.3134x over previous
//
#include <hip/hip_runtime.h>
#include <math.h>

struct Pose {
    float M[9], Tt[3], pR[9], pt[3], gR[9], gt[3], qn;
};

__device__ __forceinline__ float smooth_l1f(float x, float y) {
    float d = fabsf(x - y);
    return d < 1.0f ? 0.5f * d * d : d - 0.5f;
}

// row-major 3x3 -> quaternion, matching the reference's branch selection
// (tr>0 -> case 0, else 1+argmax(diag) with first-max tie-break)
__device__ void mat2quat_dev(const float* R, float* q) {
    float R00=R[0],R01=R[1],R02=R[2];
    float R10=R[3],R11=R[4],R12=R[5];
    float R20=R[6],R21=R[7],R22=R[8];
    float tr = R00 + R11 + R22;
    float t;
    if (tr > 0.0f) {
        t = 1.0f + tr;
        q[0]=t; q[1]=R21-R12; q[2]=R02-R20; q[3]=R10-R01;
    } else {
        int sel = 1; float best = R00;
        if (R11 > best) { sel = 2; best = R11; }
        if (R22 > best) { sel = 3; }
        if (sel == 1)      { t = 1.0f+R00-R11-R22; q[0]=R21-R12; q[1]=t; q[2]=R01+R10; q[3]=R02+R20; }
        else if (sel == 2) { t = 1.0f-R00+R11-R22; q[0]=R02-R20; q[1]=R01+R10; q[2]=t; q[3]=R12+R21; }
        else               { t = 1.0f-R00-R11+R22; q[0]=R10-R01; q[1]=R02+R20; q[2]=R12+R21; q[3]=t; }
    }
    float s = 0.5f / sqrtf(fmaxf(t, 1e-12f));
    q[0]*=s; q[1]*=s; q[2]*=s; q[3]*=s;
}

// All the small per-batch matrix algebra: fused transform for the point loss
// (M = gR^T*pR - I, Tt = gR^T*(pt-gt)) plus intermediates for t/r/qn terms.
__device__ void compute_pose(int b,
                             const float* __restrict__ pred_t,
                             const float* __restrict__ pred_q,
                             const float* __restrict__ gtT,
                             const float* __restrict__ initT,
                             Pose& P)
{
    float tx=pred_t[b*3+0], ty=pred_t[b*3+1], tz=pred_t[b*3+2];
    float q0=pred_q[b*4+0], q1=pred_q[b*4+1], q2=pred_q[b*4+2], q3=pred_q[b*4+3];
    float nsq = q0*q0+q1*q1+q2*q2+q3*q3;
    P.qn = (nsq-1.0f)*(nsq-1.0f);
    float inv = rsqrtf(nsq);
    float w=q0*inv, x=q1*inv, y=q2*inv, z=q3*inv;
    float R[9];
    R[0]=1.0f-2.0f*(y*y+z*z); R[1]=2.0f*(x*y-w*z);      R[2]=2.0f*(x*z+w*y);
    R[3]=2.0f*(x*y+w*z);      R[4]=1.0f-2.0f*(x*x+z*z); R[5]=2.0f*(y*z-w*x);
    R[6]=2.0f*(x*z-w*y);      R[7]=2.0f*(y*z+w*x);      R[8]=1.0f-2.0f*(x*x+y*y);

    float iR[9], it[3];
    for (int i=0;i<3;i++){
        for (int j=0;j<3;j++){
            iR[i*3+j]=initT[b*16+i*4+j];
            P.gR[i*3+j]=gtT[b*16+i*4+j];
        }
        it[i]=initT[b*16+i*4+3];
        P.gt[i]=gtT[b*16+i*4+3];
    }
    // inv(T_pred) @ init : pR = R^T iR, pt = R^T (it - t)
    for (int i=0;i<3;i++){
        for (int j=0;j<3;j++)
            P.pR[i*3+j] = R[0+i]*iR[0+j] + R[3+i]*iR[3+j] + R[6+i]*iR[6+j];
        P.pt[i] = R[0+i]*(it[0]-tx) + R[3+i]*(it[1]-ty) + R[6+i]*(it[2]-tz);
    }
    // RT = inv(gt) @ [pR pt] : M = gR^T pR - I, Tt = gR^T (pt - gt)
    for (int i=0;i<3;i++){
        for (int j=0;j<3;j++)
            P.M[i*3+j] = P.gR[0+i]*P.pR[0+j] + P.gR[3+i]*P.pR[3+j] + P.gR[6+i]*P.pR[6+j];
        P.Tt[i] = P.gR[0+i]*(P.pt[0]-P.gt[0]) + P.gR[3+i]*(P.pt[1]-P.gt[1]) + P.gR[6+i]*(P.pt[2]-P.gt[2]);
    }
    P.M[0]-=1.0f; P.M[4]-=1.0f; P.M[8]-=1.0f;   // pts - pcs = M*p + Tt
}

// Main kernel: unit-stride float4 global loads staged through LDS (1024
// points = 12 KB per tile), conflict-free stride-3-dword LDS reads,
// per-block partial sums to unique slots (no atomics, no zero-init).
__global__ __launch_bounds__(256) void pc_fused(const float* __restrict__ pcs,
                                                const int* __restrict__ mask,
                                                const float* __restrict__ pred_t,
                                                const float* __restrict__ pred_q,
                                                const float* __restrict__ gtT,
                                                const float* __restrict__ initT,
                                                float* __restrict__ errS,
                                                float* __restrict__ maskS,
                                                int N, int bpb)
{
    int b   = blockIdx.x / bpb;
    int blk = blockIdx.x - b*bpb;
    int t   = threadIdx.x;

    __shared__ float sMT[12];
    __shared__ float sP[3072];      // 1024 points (SoA-free xyz stream), 12 KB
    float4* sP4 = (float4*)sP;

    if (t == 0) {
        Pose P;
        compute_pose(b, pred_t, pred_q, gtT, initT, P);
        #pragma unroll
        for (int k=0;k<9;k++) sMT[k]=P.M[k];
        sMT[9]=P.Tt[0]; sMT[10]=P.Tt[1]; sMT[11]=P.Tt[2];
    }
    __syncthreads();
    float m00=sMT[0], m01=sMT[1], m02=sMT[2];
    float m10=sMT[3], m11=sMT[4], m12=sMT[5];
    float m20=sMT[6], m21=sMT[7], m22=sMT[8];
    float t0 =sMT[9], t1 =sMT[10], t2 =sMT[11];

    const float4* pbase = (const float4*)(pcs + (size_t)b * N * 3);
    const int*    mbase = mask + (size_t)b * N;
    float esum = 0.0f, msum = 0.0f;

    int ntiles = N >> 10;           // full 1024-point tiles
    for (int tile = blk; tile < ntiles; tile += bpb) {
        const float4* src = pbase + (size_t)tile * 768;
        __syncthreads();            // protect previous tile's LDS reads
        sP4[t      ] = src[t      ];
        sP4[t + 256] = src[t + 256];
        sP4[t + 512] = src[t + 512];
        __syncthreads();
        int gbase = tile << 10;
        #pragma unroll
        for (int k=0;k<4;k++){
            int p = t + (k<<8);     // local point 0..1023
            float x = sP[3*p], y = sP[3*p+1], z = sP[3*p+2];
            float mm = (float)mbase[gbase + p];
            float dx = m00*x + m01*y + m02*z + t0;
            float dy = m10*x + m11*y + m12*z + t1;
            float dz = m20*x + m21*y + m22*z + t2;
            esum += mm * sqrtf(dx*dx + dy*dy + dz*dz);
            msum += mm;
        }
    }
    // ragged tail (N % 1024), handled by block 0 of each batch
    if (blk == 0) {
        for (int p = (ntiles<<10) + t; p < N; p += 256) {
            float x = pcs[((size_t)b*N + p)*3 + 0];
            float y = pcs[((size_t)b*N + p)*3 + 1];
            float z = pcs[((size_t)b*N + p)*3 + 2];
            float mm = (float)mbase[p];
            float dx = m00*x + m01*y + m02*z + t0;
            float dy = m10*x + m11*y + m12*z + t1;
            float dz = m20*x + m21*y + m22*z + t2;
            esum += mm*sqrtf(dx*dx+dy*dy+dz*dz);
            msum += mm;
        }
    }

    for (int off=32; off>0; off>>=1){
        esum += __shfl_down(esum, off);
        msum += __shfl_down(msum, off);
    }
    __shared__ float sE[4], sM[4];
    int lane = t & 63, wid = t >> 6;
    if (lane==0){ sE[wid]=esum; sM[wid]=msum; }
    __syncthreads();
    if (t==0){
        errS [blockIdx.x] = sE[0]+sE[1]+sE[2]+sE[3];
        maskS[blockIdx.x] = sM[0]+sM[1]+sM[2]+sM[3];
    }
}

// 256 threads (4 waves): wave w reduces batches {w, w+4, ...}; wave 0's
// lanes < B compute the tiny scalar loss terms.
__global__ void finish_kernel(const float* __restrict__ errS,
                              const float* __restrict__ maskS,
                              const float* __restrict__ pred_t,
                              const float* __restrict__ pred_q,
                              const float* __restrict__ gtT,
                              const float* __restrict__ initT,
                              float* __restrict__ out, int B, int bpb)
{
    int t = threadIdx.x, lane = t & 63, w = t >> 6;
    __shared__ double sPC[4];
    double acc = 0.0;
    for (int b = w; b < B; b += 4) {
        float e=0.0f, m=0.0f;
        for (int k=lane; k<bpb; k+=64){ e += errS[b*bpb+k]; m += maskS[b*bpb+k]; }
        for (int off=32; off>0; off>>=1){
            e += __shfl_down(e, off);
            m += __shfl_down(m, off);
        }
        if (lane==0) acc += (double)e / (double)m;
    }
    if (lane==0) sPC[w] = acc;

    float partial = 0.0f;
    if (t < B) {   // B <= 64: all in wave 0
        Pose P;
        compute_pose(t, pred_t, pred_q, gtT, initT, P);
        float t_term = smooth_l1f(P.pt[0],P.gt[0]) + smooth_l1f(P.pt[1],P.gt[1])
                     + smooth_l1f(P.pt[2],P.gt[2]);
        float qp[4], qg[4];
        mat2quat_dev(P.pR,qp); mat2quat_dev(P.gR,qg);
        float dw  = qp[0]*qg[0] + qp[1]*qg[1] + qp[2]*qg[2] + qp[3]*qg[3];
        float cx  = qp[2]*qg[3]-qp[3]*qg[2];
        float cy  = qp[3]*qg[1]-qp[1]*qg[3];
        float cz  = qp[1]*qg[2]-qp[2]*qg[1];
        float dvx = -qp[0]*qg[1] + qg[0]*qp[1] - cx;
        float dvy = -qp[0]*qg[2] + qg[0]*qp[2] - cy;
        float dvz = -qp[0]*qg[3] + qg[0]*qp[3] - cz;
        float r_term = 2.0f*atan2f(sqrtf(dvx*dvx+dvy*dvy+dvz*dvz), fabsf(dw));
        partial = (1.0f*t_term + 0.5f*r_term + 0.5f*P.qn) / (float)B;
    }
    if (w==0)
        for (int off=32; off>0; off>>=1) partial += __shfl_down(partial, off);
    __syncthreads();
    if (t==0){
        double pc = sPC[0]+sPC[1]+sPC[2]+sPC[3];
        out[0] = partial + 0.5f * (float)(pc / (double)B);
    }
}

extern "C" void kernel_launch(void* const* d_in, const int* in_sizes, int n_in,
                              void* d_out, int out_size, void* d_ws, size_t ws_size,
                              hipStream_t stream)
{
    const float* pred_t = (const float*)d_in[0];
    const float* pred_q = (const float*)d_in[1];
    const float* pcs    = (const float*)d_in[2];
    const float* gtT    = (const float*)d_in[3];
    const float* initT  = (const float*)d_in[4];
    const int*   mask   = (const int*)d_in[5];

    int B = in_sizes[0] / 3;
    int N = in_sizes[2] / (B * 3);

    int bpb = 256;  // blocks per batch -> B*bpb total blocks
    float* errS  = (float*)d_ws;       // [B*bpb] always fully written
    float* maskS = errS + B*bpb;       // [B*bpb]
    float* out   = (float*)d_out;

    pc_fused<<<B*bpb, 256, 0, stream>>>(pcs, mask, pred_t, pred_q, gtT, initT,
                                        errS, maskS, N, bpb);
    finish_kernel<<<1, 256, 0, stream>>>(errS, maskS, pred_t, pred_q, gtT, initT,
                                         out, B, bpb);
}

// Round 4
// 31.066 us; speedup vs baseline: 1.4992x; 1.0426x over previous
//
#include <hip/hip_runtime.h>
#include <math.h>

struct Pose {
    float M[9], Tt[3], pR[9], pt[3], gR[9], gt[3], qn;
};

__device__ __forceinline__ float smooth_l1f(float x, float y) {
    float d = fabsf(x - y);
    return d < 1.0f ? 0.5f * d * d : d - 0.5f;
}

// row-major 3x3 -> quaternion, matching the reference's branch selection
// (tr>0 -> case 0, else 1+argmax(diag) with first-max tie-break)
__device__ void mat2quat_dev(const float* R, float* q) {
    float R00=R[0],R01=R[1],R02=R[2];
    float R10=R[3],R11=R[4],R12=R[5];
    float R20=R[6],R21=R[7],R22=R[8];
    float tr = R00 + R11 + R22;
    float t;
    if (tr > 0.0f) {
        t = 1.0f + tr;
        q[0]=t; q[1]=R21-R12; q[2]=R02-R20; q[3]=R10-R01;
    } else {
        int sel = 1; float best = R00;
        if (R11 > best) { sel = 2; best = R11; }
        if (R22 > best) { sel = 3; }
        if (sel == 1)      { t = 1.0f+R00-R11-R22; q[0]=R21-R12; q[1]=t; q[2]=R01+R10; q[3]=R02+R20; }
        else if (sel == 2) { t = 1.0f-R00+R11-R22; q[0]=R02-R20; q[1]=R01+R10; q[2]=t; q[3]=R12+R21; }
        else               { t = 1.0f-R00-R11+R22; q[0]=R10-R01; q[1]=R02+R20; q[2]=R12+R21; q[3]=t; }
    }
    float s = 0.5f / sqrtf(fmaxf(t, 1e-12f));
    q[0]*=s; q[1]*=s; q[2]*=s; q[3]*=s;
}

// All the small per-batch matrix algebra: fused transform for the point loss
// (M = gR^T*pR - I, Tt = gR^T*(pt-gt)) plus intermediates for t/r/qn terms.
__device__ void compute_pose(int b,
                             const float* __restrict__ pred_t,
                             const float* __restrict__ pred_q,
                             const float* __restrict__ gtT,
                             const float* __restrict__ initT,
                             Pose& P)
{
    float tx=pred_t[b*3+0], ty=pred_t[b*3+1], tz=pred_t[b*3+2];
    float q0=pred_q[b*4+0], q1=pred_q[b*4+1], q2=pred_q[b*4+2], q3=pred_q[b*4+3];
    float nsq = q0*q0+q1*q1+q2*q2+q3*q3;
    P.qn = (nsq-1.0f)*(nsq-1.0f);
    float inv = rsqrtf(nsq);
    float w=q0*inv, x=q1*inv, y=q2*inv, z=q3*inv;
    float R[9];
    R[0]=1.0f-2.0f*(y*y+z*z); R[1]=2.0f*(x*y-w*z);      R[2]=2.0f*(x*z+w*y);
    R[3]=2.0f*(x*y+w*z);      R[4]=1.0f-2.0f*(x*x+z*z); R[5]=2.0f*(y*z-w*x);
    R[6]=2.0f*(x*z-w*y);      R[7]=2.0f*(y*z+w*x);      R[8]=1.0f-2.0f*(x*x+y*y);

    float iR[9], it[3];
    for (int i=0;i<3;i++){
        for (int j=0;j<3;j++){
            iR[i*3+j]=initT[b*16+i*4+j];
            P.gR[i*3+j]=gtT[b*16+i*4+j];
        }
        it[i]=initT[b*16+i*4+3];
        P.gt[i]=gtT[b*16+i*4+3];
    }
    // inv(T_pred) @ init : pR = R^T iR, pt = R^T (it - t)
    for (int i=0;i<3;i++){
        for (int j=0;j<3;j++)
            P.pR[i*3+j] = R[0+i]*iR[0+j] + R[3+i]*iR[3+j] + R[6+i]*iR[6+j];
        P.pt[i] = R[0+i]*(it[0]-tx) + R[3+i]*(it[1]-ty) + R[6+i]*(it[2]-tz);
    }
    // RT = inv(gt) @ [pR pt] : M = gR^T pR - I, Tt = gR^T (pt - gt)
    for (int i=0;i<3;i++){
        for (int j=0;j<3;j++)
            P.M[i*3+j] = P.gR[0+i]*P.pR[0+j] + P.gR[3+i]*P.pR[3+j] + P.gR[6+i]*P.pR[6+j];
        P.Tt[i] = P.gR[0+i]*(P.pt[0]-P.gt[0]) + P.gR[3+i]*(P.pt[1]-P.gt[1]) + P.gR[6+i]*(P.pt[2]-P.gt[2]);
    }
    P.M[0]-=1.0f; P.M[4]-=1.0f; P.M[8]-=1.0f;   // pts - pcs = M*p + Tt
}

#define TP  512   // points per tile
#define F4T 384   // float4s of pcs per tile (TP*3/4)
#define M4T 128   // int4s of mask per tile (TP/4)

// Main kernel: every block gets an identical contiguous chunk (multiple of 4
// points) of one batch -> no load imbalance. Tiles of 512 points are staged
// through double-buffered LDS with register prefetch: loads for tile i+1 are
// in flight during compute of tile i; ONE barrier per tile. All global loads
// unit-stride float4/int4; all LDS reads conflict-free (stride-3 dwords).
__global__ __launch_bounds__(256) void pc_fused(const float* __restrict__ pcs,
                                                const int* __restrict__ mask,
                                                const float* __restrict__ pred_t,
                                                const float* __restrict__ pred_q,
                                                const float* __restrict__ gtT,
                                                const float* __restrict__ initT,
                                                float* __restrict__ errS,
                                                float* __restrict__ maskS,
                                                int N, int bpb, int chunk)
{
    int b   = blockIdx.x / bpb;
    int blk = blockIdx.x - b*bpb;
    int t   = threadIdx.x;

    __shared__ float sMT[12];
    __shared__ float sP[2][F4T*4];   // 2 x 1536 floats = 12 KB
    __shared__ float sK[2][TP];      // 2 x 512 floats  =  4 KB
    __shared__ float sE[4], sM[4];

    int r0 = blk * chunk;
    if (r0 >= N) {   // fully-idle block (defensive; not hit with current shapes)
        if (t==0){ errS[blockIdx.x]=0.0f; maskS[blockIdx.x]=0.0f; }
        return;
    }
    int my_pts = N - r0; if (my_pts > chunk) my_pts = chunk;   // multiple of 4
    int nt    = (my_pts + TP - 1) / TP;
    int my_f4 = (my_pts * 3) >> 2;
    int my_m4 = my_pts >> 2;

    const float4* pf4 = (const float4*)pcs  + ((size_t)b*N + r0)*3/4;
    const int4*   mi4 = (const int4*)  mask + ((size_t)b*N + r0)/4;

    if (t == 0) {
        Pose P;
        compute_pose(b, pred_t, pred_q, gtT, initT, P);
        #pragma unroll
        for (int k=0;k<9;k++) sMT[k]=P.M[k];
        sMT[9]=P.Tt[0]; sMT[10]=P.Tt[1]; sMT[11]=P.Tt[2];
    }

    float4 rA = make_float4(0,0,0,0);
    float4 rB = make_float4(0,0,0,0);
    float4 rM = make_float4(0,0,0,0);

    // stage tile ti's data into registers (guards only on the partial tile)
    auto stage = [&](int ti) {
        int fbase = ti * F4T;
        bool full = (ti*TP + TP <= my_pts);
        if (full) {
            rA = pf4[fbase + t];
            if (t < 128) {
                rB = pf4[fbase + 256 + t];
                int4 m = mi4[ti*M4T + t];
                rM = make_float4((float)m.x,(float)m.y,(float)m.z,(float)m.w);
            }
        } else {
            int s0 = fbase + t;
            rA = (s0 < my_f4) ? pf4[s0] : make_float4(0,0,0,0);
            if (t < 128) {
                int s1 = fbase + 256 + t;
                rB = (s1 < my_f4) ? pf4[s1] : make_float4(0,0,0,0);
                int s2 = ti*M4T + t;
                if (s2 < my_m4) {
                    int4 m = mi4[s2];
                    rM = make_float4((float)m.x,(float)m.y,(float)m.z,(float)m.w);
                } else rM = make_float4(0,0,0,0);
            }
        }
    };
    auto wr = [&](int buf) {
        ((float4*)sP[buf])[t] = rA;
        if (t < 128) {
            ((float4*)sP[buf])[256 + t] = rB;
            ((float4*)sK[buf])[t]       = rM;
        }
    };

    stage(0);
    __syncthreads();                 // sMT ready
    float m00=sMT[0], m01=sMT[1], m02=sMT[2];
    float m10=sMT[3], m11=sMT[4], m12=sMT[5];
    float m20=sMT[6], m21=sMT[7], m22=sMT[8];
    float t0 =sMT[9], t1 =sMT[10], t2 =sMT[11];
    wr(0);
    __syncthreads();                 // buf0 ready

    float esum = 0.0f, msum = 0.0f;
    for (int ti = 0; ti < nt; ti++) {
        int cur = ti & 1;
        if (ti + 1 < nt) stage(ti + 1);      // issue next tile's loads early
        #pragma unroll
        for (int k = 0; k < 2; k++) {
            int p = t + (k << 8);            // 0..511, conflict-free stride-3 reads
            float x = sP[cur][3*p], y = sP[cur][3*p+1], z = sP[cur][3*p+2];
            float mm = sK[cur][p];
            float dx = fmaf(m00,x, fmaf(m01,y, fmaf(m02,z, t0)));
            float dy = fmaf(m10,x, fmaf(m11,y, fmaf(m12,z, t1)));
            float dz = fmaf(m20,x, fmaf(m21,y, fmaf(m22,z, t2)));
            esum = fmaf(mm, sqrtf(fmaf(dx,dx, fmaf(dy,dy, dz*dz))), esum);
            msum += mm;
        }
        if (ti + 1 < nt) wr(cur ^ 1);        // write-late into the other buffer
        __syncthreads();                     // one barrier per tile
    }

    for (int off=32; off>0; off>>=1){
        esum += __shfl_down(esum, off);
        msum += __shfl_down(msum, off);
    }
    int lane = t & 63, wid = t >> 6;
    if (lane==0){ sE[wid]=esum; sM[wid]=msum; }
    __syncthreads();
    if (t==0){
        errS [blockIdx.x] = sE[0]+sE[1]+sE[2]+sE[3];
        maskS[blockIdx.x] = sM[0]+sM[1]+sM[2]+sM[3];
    }
}

// 256 threads (4 waves): wave w reduces batches {w, w+4, ...}; wave 0's
// lanes < B compute the tiny scalar loss terms.
__global__ void finish_kernel(const float* __restrict__ errS,
                              const float* __restrict__ maskS,
                              const float* __restrict__ pred_t,
                              const float* __restrict__ pred_q,
                              const float* __restrict__ gtT,
                              const float* __restrict__ initT,
                              float* __restrict__ out, int B, int bpb)
{
    int t = threadIdx.x, lane = t & 63, w = t >> 6;
    __shared__ double sPC[4];
    double acc = 0.0;
    for (int b = w; b < B; b += 4) {
        float e=0.0f, m=0.0f;
        for (int k=lane; k<bpb; k+=64){ e += errS[b*bpb+k]; m += maskS[b*bpb+k]; }
        for (int off=32; off>0; off>>=1){
            e += __shfl_down(e, off);
            m += __shfl_down(m, off);
        }
        if (lane==0) acc += (double)e / (double)m;
    }
    if (lane==0) sPC[w] = acc;

    float partial = 0.0f;
    if (t < B) {   // B <= 64: all in wave 0
        Pose P;
        compute_pose(t, pred_t, pred_q, gtT, initT, P);
        float t_term = smooth_l1f(P.pt[0],P.gt[0]) + smooth_l1f(P.pt[1],P.gt[1])
                     + smooth_l1f(P.pt[2],P.gt[2]);
        float qp[4], qg[4];
        mat2quat_dev(P.pR,qp); mat2quat_dev(P.gR,qg);
        float dw  = qp[0]*qg[0] + qp[1]*qg[1] + qp[2]*qg[2] + qp[3]*qg[3];
        float cx  = qp[2]*qg[3]-qp[3]*qg[2];
        float cy  = qp[3]*qg[1]-qp[1]*qg[3];
        float cz  = qp[1]*qg[2]-qp[2]*qg[1];
        float dvx = -qp[0]*qg[1] + qg[0]*qp[1] - cx;
        float dvy = -qp[0]*qg[2] + qg[0]*qp[2] - cy;
        float dvz = -qp[0]*qg[3] + qg[0]*qp[3] - cz;
        float r_term = 2.0f*atan2f(sqrtf(dvx*dvx+dvy*dvy+dvz*dvz), fabsf(dw));
        partial = (1.0f*t_term + 0.5f*r_term + 0.5f*P.qn) / (float)B;
    }
    if (w==0)
        for (int off=32; off>0; off>>=1) partial += __shfl_down(partial, off);
    __syncthreads();
    if (t==0){
        double pc = sPC[0]+sPC[1]+sPC[2]+sPC[3];
        out[0] = partial + 0.5f * (float)(pc / (double)B);
    }
}

extern "C" void kernel_launch(void* const* d_in, const int* in_sizes, int n_in,
                              void* d_out, int out_size, void* d_ws, size_t ws_size,
                              hipStream_t stream)
{
    const float* pred_t = (const float*)d_in[0];
    const float* pred_q = (const float*)d_in[1];
    const float* pcs    = (const float*)d_in[2];
    const float* gtT    = (const float*)d_in[3];
    const float* initT  = (const float*)d_in[4];
    const int*   mask   = (const int*)d_in[5];

    int B = in_sizes[0] / 3;
    int N = in_sizes[2] / (B * 3);

    int bpb   = 256;                                   // blocks per batch
    int chunk = (((N + bpb - 1) / bpb) + 3) & ~3;      // points/block, mult of 4

    float* errS  = (float*)d_ws;       // [B*bpb] always fully written
    float* maskS = errS + B*bpb;       // [B*bpb]
    float* out   = (float*)d_out;

    pc_fused<<<B*bpb, 256, 0, stream>>>(pcs, mask, pred_t, pred_q, gtT, initT,
                                        errS, maskS, N, bpb, chunk);
    finish_kernel<<<1, 256, 0, stream>>>(errS, maskS, pred_t, pred_q, gtT, initT,
                                         out, B, bpb);
}